// Round 1
// baseline (415.977 us; speedup 1.0000x reference)
//
#include <hip/hip_runtime.h>
#include <cstddef>
#include <cstdint>

#define NB 8
#define SEQ 4096
#define HIDDIM 4096
#define NHEAD 32
#define HDIM 128
#define FFNDIM 16384
#define ATTN_SCALE 0.08838834764831845f

__device__ __forceinline__ float wave_sum(float v) {
#pragma unroll
  for (int off = 32; off > 0; off >>= 1) v += __shfl_xor(v, off, 64);
  return v;
}

// positions may arrive as int32 (harness default) or int64 (reference dtype).
// If int64, the odd 32-bit words (high halves) of the first 4 values are 0.
__device__ __forceinline__ int get_pos(const int* __restrict__ p, int b) {
  const bool is64 = ((p[1] | p[3] | p[5] | p[7]) == 0);
  return is64 ? p[2 * b] : p[b];
}

// ---------- LayerNorm1p: (x-mu)*rsqrt(var+eps)*(w+1)+b, output transposed (i,b)
__global__ __launch_bounds__(256) void ln_rows(const float* __restrict__ in,
                                               const float* __restrict__ w,
                                               const float* __restrict__ bias,
                                               float* __restrict__ out_t) {
  __shared__ float row[HIDDIM];
  __shared__ float red[4];
  const int b = blockIdx.x, t = threadIdx.x;
  float s = 0.f;
  for (int i = t; i < HIDDIM; i += 256) {
    const float v = in[(size_t)b * HIDDIM + i];
    row[i] = v;
    s += v;
  }
  s = wave_sum(s);
  if ((t & 63) == 0) red[t >> 6] = s;
  __syncthreads();
  const float mean = (red[0] + red[1] + red[2] + red[3]) * (1.0f / HIDDIM);
  __syncthreads();
  float vs = 0.f;
  for (int i = t; i < HIDDIM; i += 256) {
    const float d = row[i] - mean;
    vs += d * d;
  }
  vs = wave_sum(vs);
  if ((t & 63) == 0) red[t >> 6] = vs;
  __syncthreads();
  const float var = (red[0] + red[1] + red[2] + red[3]) * (1.0f / HIDDIM);
  const float rs = rsqrtf(var + 1e-5f);
  for (int i = t; i < HIDDIM; i += 256) {
    out_t[(size_t)i * NB + b] = (row[i] - mean) * rs * (w[i] + 1.0f) + bias[i];
  }
}

// ---------- Skinny GEMM, M=8, split-K into partials. xt is (K, 8) transposed.
// part layout: [chunk][b][N]
template <int KCHUNK>
__global__ __launch_bounds__(256) void gemm8(const float* __restrict__ W,
                                             const float* __restrict__ xt,
                                             float* __restrict__ part, int N) {
  const int j0 = (blockIdx.x * 256 + threadIdx.x) * 4;
  const size_t i0 = (size_t)blockIdx.y * KCHUNK;
  const float* __restrict__ wp = W + i0 * N + j0;
  const float* __restrict__ xp = xt + i0 * NB;
  float4 a0 = {0, 0, 0, 0}, a1 = {0, 0, 0, 0}, a2 = {0, 0, 0, 0}, a3 = {0, 0, 0, 0};
  float4 a4 = {0, 0, 0, 0}, a5 = {0, 0, 0, 0}, a6 = {0, 0, 0, 0}, a7 = {0, 0, 0, 0};
#pragma unroll 4
  for (int i = 0; i < KCHUNK; ++i) {
    const float4 w = *reinterpret_cast<const float4*>(wp + (size_t)i * N);
    const float4 xa = *reinterpret_cast<const float4*>(xp + i * NB);
    const float4 xb = *reinterpret_cast<const float4*>(xp + i * NB + 4);
#define ACC4(A, sxx)                                                          \
  A.x = fmaf(sxx, w.x, A.x);                                                  \
  A.y = fmaf(sxx, w.y, A.y);                                                  \
  A.z = fmaf(sxx, w.z, A.z);                                                  \
  A.w = fmaf(sxx, w.w, A.w);
    ACC4(a0, xa.x) ACC4(a1, xa.y) ACC4(a2, xa.z) ACC4(a3, xa.w)
    ACC4(a4, xb.x) ACC4(a5, xb.y) ACC4(a6, xb.z) ACC4(a7, xb.w)
#undef ACC4
  }
  float* op = part + (size_t)blockIdx.y * NB * N + j0;
  *reinterpret_cast<float4*>(op) = a0; op += N;
  *reinterpret_cast<float4*>(op) = a1; op += N;
  *reinterpret_cast<float4*>(op) = a2; op += N;
  *reinterpret_cast<float4*>(op) = a3; op += N;
  *reinterpret_cast<float4*>(op) = a4; op += N;
  *reinterpret_cast<float4*>(op) = a5; op += N;
  *reinterpret_cast<float4*>(op) = a6; op += N;
  *reinterpret_cast<float4*>(op) = a7;
}

// ---------- reduce qkv partials + RoPE on q,k; write q/k/v (b, h*128+d) fp32
__global__ __launch_bounds__(128) void rope_reduce(const float* __restrict__ part, int nchunk,
                                                   const int* __restrict__ posp,
                                                   float* __restrict__ qo,
                                                   float* __restrict__ ko,
                                                   float* __restrict__ vo) {
  const int blk = blockIdx.x;
  const int b = blk >> 5, h = blk & 31;
  const int d = threadIdx.x;  // 0..127
  const int col = h * HDIM + d;
  float qs = 0.f, ks = 0.f, vs = 0.f;
  for (int c = 0; c < nchunk; ++c) {
    const float* p = part + ((size_t)c * NB + b) * (3 * HIDDIM);
    qs += p[col];
    ks += p[HIDDIM + col];
    vs += p[2 * HIDDIM + col];
  }
  __shared__ float qsh[HDIM], ksh[HDIM];
  qsh[d] = qs;
  ksh[d] = ks;
  __syncthreads();
  float qv = qs, kv = ks;
  if (d < 64) {
    const int f = d & 31;
    const float ang = (float)get_pos(posp, b) * powf(10000.0f, -(float)f * (1.0f / 32.0f));
    const float cs = cosf(ang), sn = sinf(ang);
    if (d < 32) {
      qv = qsh[d] * cs - qsh[d + 32] * sn;
      kv = ksh[d] * cs - ksh[d + 32] * sn;
    } else {
      qv = qsh[d] * cs + qsh[d - 32] * sn;
      kv = ksh[d] * cs + ksh[d - 32] * sn;
    }
  }
  qo[(size_t)b * HIDDIM + col] = qv;
  ko[(size_t)b * HIDDIM + col] = kv;
  vo[(size_t)b * HIDDIM + col] = vs;
}

// ---------- flash-decoding: per (chunk, h, b), online softmax over <=256 rows
__global__ __launch_bounds__(256) void attn_split(
    const float* __restrict__ kc, const float* __restrict__ vc,
    const float* __restrict__ q, const float* __restrict__ kn,
    const float* __restrict__ vn, const int* __restrict__ posp,
    float* __restrict__ Mp, float* __restrict__ Lp, float* __restrict__ Ap) {
  const int c = blockIdx.x, h = blockIdx.y, b = blockIdx.z;
  const int pos = get_pos(posp, b);
  const int s0 = c * 256;
  if (s0 > pos) return;
  const int s1 = min(s0 + 256, pos + 1);
  const int wid = threadIdx.x >> 6, lane = threadIdx.x & 63;
  const int dd = 2 * lane;
  const float2 qv = *reinterpret_cast<const float2*>(q + (size_t)b * HIDDIM + h * HDIM + dd);
  const float* kb = kc + ((size_t)b * SEQ * NHEAD + h) * HDIM + dd;
  const float* vb = vc + ((size_t)b * SEQ * NHEAD + h) * HDIM + dd;
  const float* knp = kn + (size_t)b * HIDDIM + h * HDIM + dd;
  const float* vnp = vn + (size_t)b * HIDDIM + h * HDIM + dd;
  float m = -INFINITY, l = 0.f;
  float2 acc = {0.f, 0.f};
  for (int s = s0 + wid; s < s1; s += 4) {
    const float* kp = (s == pos) ? knp : kb + (size_t)s * (NHEAD * HDIM);
    const float* vp = (s == pos) ? vnp : vb + (size_t)s * (NHEAD * HDIM);
    const float2 kk = *reinterpret_cast<const float2*>(kp);
    const float2 vv = *reinterpret_cast<const float2*>(vp);
    float p = qv.x * kk.x + qv.y * kk.y;
    p = wave_sum(p) * ATTN_SCALE;
    const float mn = fmaxf(m, p);
    const float cf = __expf(m - mn);
    const float pw = __expf(p - mn);
    l = l * cf + pw;
    acc.x = acc.x * cf + pw * vv.x;
    acc.y = acc.y * cf + pw * vv.y;
    m = mn;
  }
  __shared__ float sm[4], sl[4], sa[4][HDIM];
  sa[wid][dd] = acc.x;
  sa[wid][dd + 1] = acc.y;
  if (lane == 0) { sm[wid] = m; sl[wid] = l; }
  __syncthreads();
  if (threadIdx.x < HDIM) {
    const int d = threadIdx.x;
    const float M = fmaxf(fmaxf(sm[0], sm[1]), fmaxf(sm[2], sm[3]));
    float L = 0.f, A = 0.f;
#pragma unroll
    for (int w2 = 0; w2 < 4; ++w2) {
      const float e = __expf(sm[w2] - M);
      L += e * sl[w2];
      A += e * sa[w2][d];
    }
    const size_t idx = (size_t)(b * NHEAD + h) * 16 + c;
    if (d == 0) { Mp[idx] = M; Lp[idx] = L; }
    Ap[idx * HDIM + d] = A;
  }
}

// ---------- combine chunk partials -> attn output transposed (i=h*128+d, b)
__global__ __launch_bounds__(128) void attn_combine(
    const float* __restrict__ Mp, const float* __restrict__ Lp,
    const float* __restrict__ Ap, const int* __restrict__ posp,
    float* __restrict__ out_t) {
  const int blk = blockIdx.x;
  const int b = blk >> 5, h = blk & 31;
  const int d = threadIdx.x;
  const int nc = get_pos(posp, b) / 256 + 1;
  const size_t base = (size_t)(b * NHEAD + h) * 16;
  float M = -INFINITY;
  for (int c = 0; c < nc; ++c) M = fmaxf(M, Mp[base + c]);
  float L = 0.f, A = 0.f;
  for (int c = 0; c < nc; ++c) {
    const float e = __expf(Mp[base + c] - M);
    L += e * Lp[base + c];
    A += e * Ap[(base + c) * HDIM + d];
  }
  out_t[(size_t)(h * HDIM + d) * NB + b] = A / L;
}

// ---------- out[idx] = base[idx] + sum_c part[c][idx]   (idx over 8*4096)
__global__ __launch_bounds__(256) void reduce_add(const float* __restrict__ part, int nchunk,
                                                  const float* __restrict__ base,
                                                  float* __restrict__ out) {
  const int idx = blockIdx.x * 256 + threadIdx.x;
  float v = base[idx];
  for (int c = 0; c < nchunk; ++c) v += part[(size_t)c * (NB * HIDDIM) + idx];
  out[idx] = v;
}

// ---------- reduce fc1 partials + silu-gate; write g transposed (j, b)
__global__ __launch_bounds__(256) void gate_silu(const float* __restrict__ part, int nchunk,
                                                 float* __restrict__ gt) {
  const int j = blockIdx.x * 256 + threadIdx.x;  // 0..FFN-1
  const int b = blockIdx.y;
  float h1 = 0.f, h2 = 0.f;
  for (int c = 0; c < nchunk; ++c) {
    const float* p = part + ((size_t)c * NB + b) * (2 * FFNDIM);
    h1 += p[j];
    h2 += p[FFNDIM + j];
  }
  const float g = (h1 / (1.f + __expf(-h1))) * h2;
  gt[(size_t)j * NB + b] = g;
}

extern "C" void kernel_launch(void* const* d_in, const int* in_sizes, int n_in,
                              void* d_out, int out_size, void* d_ws, size_t ws_size,
                              hipStream_t stream) {
  const float* hs = (const float*)d_in[0];
  const float* kc = (const float*)d_in[1];
  const float* vc = (const float*)d_in[2];
  const float* wqkv = (const float*)d_in[3];
  const float* wdense = (const float*)d_in[4];
  const float* wfc1 = (const float*)d_in[5];
  const float* wfc2 = (const float*)d_in[6];
  const float* ln1w = (const float*)d_in[7];
  const float* ln1b = (const float*)d_in[8];
  const float* ln2w = (const float*)d_in[9];
  const float* ln2b = (const float*)d_in[10];
  const int* posp = (const int*)d_in[11];
  float* out = (float*)d_out;

  float* ws = (float*)d_ws;
  float* x1t = ws;                 // 32768  (HID x 8 transposed)
  float* qws = x1t + 32768;        // 32768
  float* kws = qws + 32768;        // 32768
  float* vws = kws + 32768;        // 32768
  float* attnt = vws + 32768;      // 32768
  float* hidden2 = attnt + 32768;  // 32768 (natural b,i layout)
  float* x2t = hidden2 + 32768;    // 32768
  float* gt = x2t + 32768;         // 131072 (FFN x 8 transposed)
  float* Mp = gt + 131072;         // 4096
  float* Lp = Mp + 4096;           // 4096
  float* Ap = Lp + 4096;           // 524288
  float* part = Ap + 524288;       // up to 4,194,304 floats (16 MiB), reused

  // 1. LN1
  ln_rows<<<8, 256, 0, stream>>>(hs, ln1w, ln1b, x1t);
  // 2. qkv = x1 @ w_qkv  (K=4096 in 32 chunks of 128), N=12288
  gemm8<128><<<dim3(12, 32), 256, 0, stream>>>(wqkv, x1t, part, 3 * HIDDIM);
  // 3. reduce + rope -> q/k/v new-token vectors
  rope_reduce<<<256, 128, 0, stream>>>(part, 32, posp, qws, kws, vws);
  // 4. attention, flash-decoding split over 16 s-chunks
  attn_split<<<dim3(16, NHEAD, NB), 256, 0, stream>>>(kc, vc, qws, kws, vws, posp, Mp, Lp, Ap);
  // 5. combine
  attn_combine<<<256, 128, 0, stream>>>(Mp, Lp, Ap, posp, attnt);
  // 6. dense = attn @ w_dense (32 chunks of 128), N=4096
  gemm8<128><<<dim3(4, 32), 256, 0, stream>>>(wdense, attnt, part, HIDDIM);
  // 7. hidden2 = hs + sum(partials)
  reduce_add<<<128, 256, 0, stream>>>(part, 32, hs, hidden2);
  // 8. LN2
  ln_rows<<<8, 256, 0, stream>>>(hidden2, ln2w, ln2b, x2t);
  // 9. h = x2 @ w_fc1 (16 chunks of 256), N=32768
  gemm8<256><<<dim3(32, 16), 256, 0, stream>>>(wfc1, x2t, part, 2 * FFNDIM);
  // 10. g = silu(h1)*h2
  gate_silu<<<dim3(64, NB), 256, 0, stream>>>(part, 16, gt);
  // 11. y = g @ w_fc2 (64 chunks of 256), N=4096
  gemm8<256><<<dim3(4, 64), 256, 0, stream>>>(wfc2, gt, part, HIDDIM);
  // 12. out = hidden2 + sum(partials)
  reduce_add<<<128, 256, 0, stream>>>(part, 64, hidden2, out);
}